// Round 7
// baseline (183.875 us; speedup 1.0000x reference)
//
#include <hip/hip_runtime.h>
#include <hip/hip_bf16.h>

typedef __attribute__((ext_vector_type(8))) short short8;
typedef __attribute__((ext_vector_type(4))) short short4_t;
typedef __attribute__((ext_vector_type(4))) float float4_;

#define LOG2E 1.4426950408889634f

__device__ __forceinline__ short f2bf(float f) {
    unsigned int u = __builtin_bit_cast(unsigned int, f);
    u = (u + 0x7FFFu + ((u >> 16) & 1u)) >> 16;
    return (short)u;
}

// pack two floats to bf16x2 (round-half-up): low short = a, high = b
__device__ __forceinline__ unsigned pk2bf(float a, float b) {
    unsigned ua = __builtin_bit_cast(unsigned, a) + 0x8000u;
    unsigned ub = __builtin_bit_cast(unsigned, b) + 0x8000u;
    return __builtin_amdgcn_perm(ub, ua, 0x07060302);
}

__device__ __forceinline__ void gload_lds16(const short* g, short* l) {
    __builtin_amdgcn_global_load_lds((const __attribute__((address_space(1))) void*)g,
                                     (__attribute__((address_space(3))) void*)l, 16, 0, 0);
}

// PV with K=16 real data via zero-padded K=32 MFMA (HW-validated layout only):
// A/B real values at k=quad*8+{0..3} (<-> s_local=quad*4+{0..3} on both operands).
__device__ __forceinline__ float4_ pv_mfma(short4_t a, short4_t b, float4_ c) {
    short8 a8 = {a[0], a[1], a[2], a[3], 0, 0, 0, 0};
    short8 b8 = {b[0], b[1], b[2], b[3], 0, 0, 0, 0};
    return __builtin_amdgcn_mfma_f32_16x16x32_bf16(a8, b8, c, 0, 0, 0);
}

// ---------------- convert fp32 -> bf16 (fold SCALE*LOG2E into Wq; stack Wq|Wk|Wv) ----------------
__global__ __launch_bounds__(256) void cvt_kernel(
    const float* __restrict__ X, const float* __restrict__ Wq, const float* __restrict__ Wk,
    const float* __restrict__ Wv, const float* __restrict__ Wo,
    short* __restrict__ Xb, short* __restrict__ Wqkvb, short* __restrict__ Wob) {
    int i = blockIdx.x * 256 + threadIdx.x;
    const float* src; short* dst; float sc = 1.0f;
    if (i < 1048576) { src = X + (size_t)i * 4; dst = Xb + (size_t)i * 4; }
    else {
        int w = i - 1048576; int sec = w >> 16; int j = (w & 65535) * 4;
        if (sec == 0)      { src = Wq + j; dst = Wqkvb + j; sc = 0.125f * LOG2E; }
        else if (sec == 1) { src = Wk + j; dst = Wqkvb + 262144 + j; }
        else if (sec == 2) { src = Wv + j; dst = Wqkvb + 524288 + j; }
        else               { src = Wo + j; dst = Wob + j; }
    }
    float4 v = *(const float4*)src;
    short4_t o;
    o[0] = f2bf(v.x * sc); o[1] = f2bf(v.y * sc); o[2] = f2bf(v.z * sc); o[3] = f2bf(v.w * sc);
    *(short4_t*)dst = o;
}

// ---------------- fused QKV projection GEMM: C[m,n] = sum_k X[m,k]*Wqkv[n,k] ----------------
__global__ __launch_bounds__(256) void gemm_qkv(const short* __restrict__ A, const short* __restrict__ B,
                                                const int* __restrict__ mask,
                                                short* __restrict__ Qb, short* __restrict__ Kb,
                                                short* __restrict__ Vtb) {
    __shared__ short At[128 * 32];
    __shared__ short Bt[128 * 32];
    __shared__ int maskL[128];
    constexpr int K = 512;
    int tid = threadIdx.x;
    int wid = tid >> 6, lane = tid & 63;
    int quad = lane >> 4, cc = lane & 15;
    int wr = wid >> 1, wc = wid & 1;
    int m0 = blockIdx.y * 128, n0 = blockIdx.x * 128;
    if (tid < 128) maskL[tid] = mask[m0 + tid];

    float4_ acc[4][4] = {};

    for (int kk = 0; kk < K; kk += 32) {
#pragma unroll
        for (int i = 0; i < 2; ++i) {
            int lb = wid * 1024 + i * 4096 + lane * 16;
            int row = lb >> 6;
            int ke = (lb & 63) >> 1;
            gload_lds16(A + (size_t)(m0 + row) * K + kk + ke, At + (lb >> 1));
            gload_lds16(B + (size_t)(n0 + row) * K + kk + ke, Bt + (lb >> 1));
        }
        __syncthreads();
        short8 af[4], bf[4];
#pragma unroll
        for (int i = 0; i < 4; ++i) af[i] = *(const short8*)(At + (wr * 64 + i * 16 + cc) * 32 + quad * 8);
#pragma unroll
        for (int j = 0; j < 4; ++j) bf[j] = *(const short8*)(Bt + (wc * 64 + j * 16 + cc) * 32 + quad * 8);
#pragma unroll
        for (int i = 0; i < 4; ++i)
#pragma unroll
            for (int j = 0; j < 4; ++j)
                acc[i][j] = __builtin_amdgcn_mfma_f32_16x16x32_bf16(af[i], bf[j], acc[i][j], 0, 0, 0);
        __syncthreads();
    }

    int which = n0 >> 9;           // block-uniform: 0=Q, 1=K, 2=V
    int b = m0 >> 11;              // block-uniform batch
    if (which == 2) {
#pragma unroll
        for (int i = 0; i < 4; ++i) {
#pragma unroll
            for (int j = 0; j < 4; ++j) {
                int d = (n0 & 511) + wc * 64 + j * 16 + cc;
                int nn = (m0 & 2047) + wr * 64 + i * 16 + quad * 4;
                short4_t pv;
                pv[0] = f2bf(acc[i][j][0]); pv[1] = f2bf(acc[i][j][1]);
                pv[2] = f2bf(acc[i][j][2]); pv[3] = f2bf(acc[i][j][3]);
                *(short4_t*)(Vtb + ((size_t)(b * 512 + d)) * 2048 + nn) = pv;
            }
        }
    } else {
        short* dst = which ? Kb : Qb;
#pragma unroll
        for (int i = 0; i < 4; ++i) {
#pragma unroll
            for (int j = 0; j < 4; ++j) {
#pragma unroll
                for (int r = 0; r < 4; ++r) {
                    int lm = wr * 64 + i * 16 + quad * 4 + r;
                    int nn = (m0 & 2047) + lm;
                    int hd = (n0 & 511) + wc * 64 + j * 16 + cc;
                    int h = hd >> 6, dh = hd & 63;
                    float v = acc[i][j][r];
                    if (which == 1 && maskL[lm] == 0) v = 0.0f;   // zero masked K rows
                    dst[((((size_t)b * 8 + h) * 2048 + nn) * 64) + dh] = f2bf(v);
                }
            }
        }
    }
}

// ---------------- flash attention v5: r3 text + register-P delta ----------------
// Identical to the validated r3 kernel EXCEPT: P never touches LDS. Wave w owns
// s-slice w*16..w*16+15; QK^T C-layout frag is exp2'd in-register and fed to a
// zero-padded K=32 PV; each wave holds partial O[64t][64d]; cross-wave LDS
// reduction at the end. Both per-iter barriers kept; explicit vmcnt(0) drain.
__global__ __launch_bounds__(256) void attn_kernel(const short* __restrict__ Q, const short* __restrict__ Kg,
                                                   const short* __restrict__ Vt,
                                                   short* __restrict__ AO) {
    __shared__ __align__(16) char smem[40960];
    short* KbufL = (short*)smem;              // 2 x 4096 shorts
    short* VbufL = (short*)(smem + 16384);    // 2 x 4096 shorts
    float* Lw    = (float*)(smem + 32768);    // [4 w][64 t]
    float* Lfin  = (float*)(smem + 33792);    // [64 t] reciprocal sums
    float* OB0   = (float*)smem;              // after loop: [64 t][64 d] fp32
    float* OB1   = (float*)(smem + 16384);

    int tid = threadIdx.x;
    int w = tid >> 6, lane = tid & 63;
    int quad = lane >> 4, cc = lane & 15;
    int bh = blockIdx.x, b = bh >> 3, h = bh & 7;
    int t0 = blockIdx.y * 64;
    size_t kbase = (size_t)bh * 2048 * 64;
    size_t vbase = (size_t)b * 512 * 2048 + (size_t)h * 64 * 2048;

    // Q B-fragments in registers: qf[tb][kc], B[n=t=tb*16+cc][k=kc*32+quad*8+j]
    short8 qf[4][2];
#pragma unroll
    for (int tb = 0; tb < 4; ++tb)
#pragma unroll
        for (int kc = 0; kc < 2; ++kc)
            qf[tb][kc] = *(const short8*)(Q + kbase + (size_t)(t0 + tb * 16 + cc) * 64 + kc * 32 + quad * 8);

    // loop-invariant LDS offsets (shorts)
    int c7 = cc & 15 & 7;
    int koff[2], voff4[4];
#pragma unroll
    for (int kc = 0; kc < 2; ++kc)
        koff[kc] = (w * 16 + cc) * 64 + (((kc * 4 + quad) ^ c7) * 8);
#pragma unroll
    for (int db = 0; db < 4; ++db)
        voff4[db] = (db * 16 + cc) * 64 + (((w * 2 + (quad >> 1)) ^ c7) * 8) + (quad & 1) * 4;

    float4_ o[4][4] = {};                 // o[tb][db]: O[t=tb*16+quad*4+r][d=db*16+cc] (this wave's s only)
    float lp[4] = {0.f, 0.f, 0.f, 0.f};   // per-lane partial row sums, t = tb*16+cc

    // prologue: stage tile 0 into buffer 0 (r3 verbatim)
#pragma unroll
    for (int pass = 0; pass < 4; ++pass) {
        int slot = pass * 256 + tid;
        if (slot < 512) {
            int s = slot >> 3, c = slot & 7;
            gload_lds16(Kg + kbase + (size_t)s * 64 + ((c ^ (s & 7)) * 8), KbufL + slot * 8);
        } else {
            int q = slot - 512;
            int d = q >> 3, c = q & 7;
            gload_lds16(Vt + vbase + (size_t)d * 2048 + ((c ^ (d & 7)) * 8), VbufL + q * 8);
        }
    }

    for (int it = 0; it < 32; ++it) {
        int cur = it & 1;
        const short* Kt  = KbufL + cur * 4096;
        const short* Vtt = VbufL + cur * 4096;
        __asm__ volatile("s_waitcnt vmcnt(0) lgkmcnt(0)" ::: "memory");
        __syncthreads();   // DMA(it) drained+visible; prev tile's readers done with buf[cur^1]

        if (it < 31) {     // prefetch tile it+1 into the other buffer (r3 verbatim)
            int s1 = (it + 1) * 64;
            short* Kn = KbufL + (cur ^ 1) * 4096;
            short* Vn = VbufL + (cur ^ 1) * 4096;
#pragma unroll
            for (int pass = 0; pass < 4; ++pass) {
                int slot = pass * 256 + tid;
                if (slot < 512) {
                    int s = slot >> 3, c = slot & 7;
                    gload_lds16(Kg + kbase + (size_t)(s1 + s) * 64 + ((c ^ (s & 7)) * 8), Kn + slot * 8);
                } else {
                    int q = slot - 512;
                    int d = q >> 3, c = q & 7;
                    gload_lds16(Vt + vbase + (size_t)d * 2048 + s1 + ((c ^ (d & 7)) * 8), Vn + q * 8);
                }
            }
        }

        // ---- QK^T (r3 verbatim math): wave w computes S^T[s=w*16+quad*4+r][t] ----
        short8 kf0 = *(const short8*)(Kt + koff[0]);
        short8 kf1 = *(const short8*)(Kt + koff[1]);
        short4_t vf4[4];
#pragma unroll
        for (int db = 0; db < 4; ++db) vf4[db] = *(const short4_t*)(Vtt + voff4[db]);

#pragma unroll
        for (int tb = 0; tb < 4; ++tb) {
            float4_ a = {0.f, 0.f, 0.f, 0.f};
            a = __builtin_amdgcn_mfma_f32_16x16x32_bf16(kf0, qf[tb][0], a, 0, 0, 0);
            a = __builtin_amdgcn_mfma_f32_16x16x32_bf16(kf1, qf[tb][1], a, 0, 0, 0);
            float x0 = __builtin_amdgcn_exp2f(a[0]);
            float x1 = __builtin_amdgcn_exp2f(a[1]);
            float x2 = __builtin_amdgcn_exp2f(a[2]);
            float x3 = __builtin_amdgcn_exp2f(a[3]);
            lp[tb] += (x0 + x1) + (x2 + x3);
            uint2 pw; pw.x = pk2bf(x0, x1); pw.y = pk2bf(x2, x3);
            short4_t pf = __builtin_bit_cast(short4_t, pw);
#pragma unroll
            for (int db = 0; db < 4; ++db)
                o[tb][db] = pv_mfma(pf, vf4[db], o[tb][db]);
        }
        __syncthreads();   // timing parity with r3's second barrier
    }

    // ---- reduce row sums across quads (r3 verbatim) ----
#pragma unroll
    for (int tb = 0; tb < 4; ++tb) {
        lp[tb] += __shfl_xor(lp[tb], 16, 64);
        lp[tb] += __shfl_xor(lp[tb], 32, 64);
    }
    __asm__ volatile("s_waitcnt vmcnt(0) lgkmcnt(0)" ::: "memory");
    __syncthreads();   // all K/V buffer reads done; reuse as O buffers
    if (lane < 16) {
#pragma unroll
        for (int tb = 0; tb < 4; ++tb) Lw[w * 64 + tb * 16 + lane] = lp[tb];
    }
    if (w == 0) {
#pragma unroll
        for (int tb = 0; tb < 4; ++tb)
#pragma unroll
            for (int db = 0; db < 4; ++db)
#pragma unroll
                for (int r = 0; r < 4; ++r)
                    OB0[(tb * 16 + quad * 4 + r) * 64 + db * 16 + cc] = o[tb][db][r];
    } else if (w == 1) {
#pragma unroll
        for (int tb = 0; tb < 4; ++tb)
#pragma unroll
            for (int db = 0; db < 4; ++db)
#pragma unroll
                for (int r = 0; r < 4; ++r)
                    OB1[(tb * 16 + quad * 4 + r) * 64 + db * 16 + cc] = o[tb][db][r];
    }
    __syncthreads();
    if (w == 2) {
#pragma unroll
        for (int tb = 0; tb < 4; ++tb)
#pragma unroll
            for (int db = 0; db < 4; ++db)
#pragma unroll
                for (int r = 0; r < 4; ++r)
                    OB0[(tb * 16 + quad * 4 + r) * 64 + db * 16 + cc] += o[tb][db][r];
    } else if (w == 3) {
#pragma unroll
        for (int tb = 0; tb < 4; ++tb)
#pragma unroll
            for (int db = 0; db < 4; ++db)
#pragma unroll
                for (int r = 0; r < 4; ++r)
                    OB1[(tb * 16 + quad * 4 + r) * 64 + db * 16 + cc] += o[tb][db][r];
    }
    if (tid < 64) {
        float s = Lw[tid] + Lw[64 + tid] + Lw[128 + tid] + Lw[192 + tid];
        Lfin[tid] = 1.0f / s;
    }
    __syncthreads();

    // final: OB0+OB1, normalize, pack, store (1024 float4 slots over 256 threads)
#pragma unroll
    for (int p = 0; p < 4; ++p) {
        int slot = p * 256 + tid;
        int t = slot >> 4, d0 = (slot & 15) * 4;
        float inv = Lfin[t];
        int idx = t * 64 + d0;
        float v0 = (OB0[idx + 0] + OB1[idx + 0]) * inv;
        float v1 = (OB0[idx + 1] + OB1[idx + 1]) * inv;
        float v2 = (OB0[idx + 2] + OB1[idx + 2]) * inv;
        float v3 = (OB0[idx + 3] + OB1[idx + 3]) * inv;
        uint2 pw; pw.x = pk2bf(v0, v1); pw.y = pk2bf(v2, v3);
        *(uint2*)(AO + ((size_t)(b * 2048 + t0 + t)) * 512 + h * 64 + d0) = pw;
    }
}

// ---------------- output GEMM: 64M x 128N tiles (512 blocks), C fp32 ----------------
__global__ __launch_bounds__(256) void gemm_out(const short* __restrict__ A, const short* __restrict__ B,
                                                float* __restrict__ C) {
    __shared__ short At[64 * 32];
    __shared__ short Bt[128 * 32];
    constexpr int K = 512;
    int tid = threadIdx.x;
    int wid = tid >> 6, lane = tid & 63;
    int quad = lane >> 4, cc = lane & 15;
    int wr = wid >> 1, wc = wid & 1;
    int m0 = blockIdx.y * 64, n0 = blockIdx.x * 128;

    float4_ acc[2][4] = {};

    for (int kk = 0; kk < K; kk += 32) {
        {
            int row = tid >> 2, ke = (tid & 3) * 8;
            gload_lds16(A + (size_t)(m0 + row) * K + kk + ke, At + tid * 8);
            gload_lds16(B + (size_t)(n0 + row) * K + kk + ke, Bt + tid * 8);
            int row2 = (tid + 256) >> 2;
            gload_lds16(B + (size_t)(n0 + row2) * K + kk + ke, Bt + tid * 8 + 2048);
        }
        __syncthreads();
        short8 af[2], bf[4];
#pragma unroll
        for (int i = 0; i < 2; ++i) af[i] = *(const short8*)(At + (wr * 32 + i * 16 + cc) * 32 + quad * 8);
#pragma unroll
        for (int j = 0; j < 4; ++j) bf[j] = *(const short8*)(Bt + (wc * 64 + j * 16 + cc) * 32 + quad * 8);
#pragma unroll
        for (int i = 0; i < 2; ++i)
#pragma unroll
            for (int j = 0; j < 4; ++j)
                acc[i][j] = __builtin_amdgcn_mfma_f32_16x16x32_bf16(af[i], bf[j], acc[i][j], 0, 0, 0);
        __syncthreads();
    }

#pragma unroll
    for (int i = 0; i < 2; ++i)
#pragma unroll
        for (int j = 0; j < 4; ++j)
#pragma unroll
            for (int r = 0; r < 4; ++r) {
                int gm = m0 + wr * 32 + i * 16 + quad * 4 + r;
                int gn = n0 + wc * 64 + j * 16 + cc;
                C[(size_t)gm * 512 + gn] = acc[i][j][r];
            }
}

extern "C" void kernel_launch(void* const* d_in, const int* in_sizes, int n_in,
                              void* d_out, int out_size, void* d_ws, size_t ws_size,
                              hipStream_t stream) {
    const float* X  = (const float*)d_in[0];
    const int* mask = (const int*)d_in[1];
    const float* Wq = (const float*)d_in[2];
    const float* Wk = (const float*)d_in[3];
    const float* Wv = (const float*)d_in[4];
    const float* Wo = (const float*)d_in[5];

    char* ws = (char*)d_ws;
    short* Xbf   = (short*)(ws + 0);              // 8192*512*2       = 8,388,608
    short* Wqkvb = (short*)(ws + 8388608);        // 1536*512*2       = 1,572,864
    short* Wob   = (short*)(ws + 9961472);        // 512*512*2        =   524,288
    short* Qb    = (short*)(ws + 10485760);       // [b,h,n,dh] bf16  = 8,388,608
    short* Kb    = (short*)(ws + 18874368);       // [b,h,n,dh] bf16  = 8,388,608
    short* Vtb   = (short*)(ws + 27262976);       // [b,dv,n]  bf16   = 8,388,608
    short* AOb   = (short*)(ws + 35651584);       // [b,n,512] bf16   = 8,388,608

    cvt_kernel<<<5120, 256, 0, stream>>>(X, Wq, Wk, Wv, Wo, Xbf, Wqkvb, Wob);
    gemm_qkv<<<dim3(12, 64), 256, 0, stream>>>(Xbf, Wqkvb, mask, Qb, Kb, Vtb);
    attn_kernel<<<dim3(32, 32), 256, 0, stream>>>(Qb, Kb, Vtb, AOb);
    gemm_out<<<dim3(4, 128), 256, 0, stream>>>(AOb, Wob, (float*)d_out);
}

// Round 8
// 174.396 us; speedup vs baseline: 1.0543x; 1.0543x over previous
//
#include <hip/hip_runtime.h>
#include <hip/hip_bf16.h>

typedef __attribute__((ext_vector_type(8))) short short8;
typedef __attribute__((ext_vector_type(4))) short short4_t;
typedef __attribute__((ext_vector_type(4))) float float4_;

#define LOG2E 1.4426950408889634f

__device__ __forceinline__ short f2bf(float f) {
    unsigned int u = __builtin_bit_cast(unsigned int, f);
    u = (u + 0x7FFFu + ((u >> 16) & 1u)) >> 16;
    return (short)u;
}

// pack two floats to bf16x2 (round-half-up): low short = a, high = b
__device__ __forceinline__ unsigned pk2bf(float a, float b) {
    unsigned ua = __builtin_bit_cast(unsigned, a) + 0x8000u;
    unsigned ub = __builtin_bit_cast(unsigned, b) + 0x8000u;
    return __builtin_amdgcn_perm(ub, ua, 0x07060302);
}

__device__ __forceinline__ void gload_lds16(const short* g, short* l) {
    __builtin_amdgcn_global_load_lds((const __attribute__((address_space(1))) void*)g,
                                     (__attribute__((address_space(3))) void*)l, 16, 0, 0);
}

// ---------------- convert fp32 -> bf16 (fold SCALE*LOG2E into Wq; stack Wq|Wk|Wv) ----------------
__global__ __launch_bounds__(256) void cvt_kernel(
    const float* __restrict__ X, const float* __restrict__ Wq, const float* __restrict__ Wk,
    const float* __restrict__ Wv, const float* __restrict__ Wo,
    short* __restrict__ Xb, short* __restrict__ Wqkvb, short* __restrict__ Wob) {
    int i = blockIdx.x * 256 + threadIdx.x;
    const float* src; short* dst; float sc = 1.0f;
    if (i < 1048576) { src = X + (size_t)i * 4; dst = Xb + (size_t)i * 4; }
    else {
        int w = i - 1048576; int sec = w >> 16; int j = (w & 65535) * 4;
        if (sec == 0)      { src = Wq + j; dst = Wqkvb + j; sc = 0.125f * LOG2E; }
        else if (sec == 1) { src = Wk + j; dst = Wqkvb + 262144 + j; }
        else if (sec == 2) { src = Wv + j; dst = Wqkvb + 524288 + j; }
        else               { src = Wo + j; dst = Wob + j; }
    }
    float4 v = *(const float4*)src;
    short4_t o;
    o[0] = f2bf(v.x * sc); o[1] = f2bf(v.y * sc); o[2] = f2bf(v.z * sc); o[3] = f2bf(v.w * sc);
    *(short4_t*)dst = o;
}

// ---------------- fused QKV projection GEMM, BK=64, XOR-swizzled LDS ----------------
// C[m,n] = sum_k X[m,k]*Wqkv[n,k]; n<512: Q scatter; <1024: K scatter (mask-zeroed); else V^T packed
__global__ __launch_bounds__(256) void gemm_qkv(const short* __restrict__ A, const short* __restrict__ B,
                                                const int* __restrict__ mask,
                                                short* __restrict__ Qb, short* __restrict__ Kb,
                                                short* __restrict__ Vtb) {
    __shared__ short At[128 * 64];    // 16 KB, row=64 shorts, k-chunks XOR-swizzled by row&7
    __shared__ short Bt[128 * 64];
    __shared__ int maskL[128];
    constexpr int K = 512;
    int tid = threadIdx.x;
    int wid = tid >> 6, lane = tid & 63;
    int quad = lane >> 4, cc = lane & 15;
    int c7 = cc & 7;
    int wr = wid >> 1, wc = wid & 1;
    int m0 = blockIdx.y * 128, n0 = blockIdx.x * 128;
    if (tid < 128) maskL[tid] = mask[m0 + tid];

    float4_ acc[4][4] = {};

    for (int kk = 0; kk < K; kk += 64) {
#pragma unroll
        for (int p = 0; p < 4; ++p) {
            int slot = p * 256 + tid;          // 0..1023
            int r = slot >> 3, c = slot & 7;
            int cs = (c ^ (r & 7)) * 8;        // swizzled k-element offset within row
            gload_lds16(A + (size_t)(m0 + r) * K + kk + cs, At + slot * 8);
            gload_lds16(B + (size_t)(n0 + r) * K + kk + cs, Bt + slot * 8);
        }
        __syncthreads();
#pragma unroll
        for (int kc = 0; kc < 2; ++kc) {
            short8 af[4], bf[4];
#pragma unroll
            for (int i = 0; i < 4; ++i)
                af[i] = *(const short8*)(At + (wr * 64 + i * 16 + cc) * 64 + (((kc * 4 + quad) ^ c7) * 8));
#pragma unroll
            for (int j = 0; j < 4; ++j)
                bf[j] = *(const short8*)(Bt + (wc * 64 + j * 16 + cc) * 64 + (((kc * 4 + quad) ^ c7) * 8));
#pragma unroll
            for (int i = 0; i < 4; ++i)
#pragma unroll
                for (int j = 0; j < 4; ++j)
                    acc[i][j] = __builtin_amdgcn_mfma_f32_16x16x32_bf16(af[i], bf[j], acc[i][j], 0, 0, 0);
        }
        __syncthreads();
    }

    int which = n0 >> 9;           // block-uniform: 0=Q, 1=K, 2=V
    int b = m0 >> 11;              // block-uniform batch
    if (which == 2) {
#pragma unroll
        for (int i = 0; i < 4; ++i) {
#pragma unroll
            for (int j = 0; j < 4; ++j) {
                int d = (n0 & 511) + wc * 64 + j * 16 + cc;
                int nn = (m0 & 2047) + wr * 64 + i * 16 + quad * 4;
                short4_t pv;
                pv[0] = f2bf(acc[i][j][0]); pv[1] = f2bf(acc[i][j][1]);
                pv[2] = f2bf(acc[i][j][2]); pv[3] = f2bf(acc[i][j][3]);
                *(short4_t*)(Vtb + ((size_t)(b * 512 + d)) * 2048 + nn) = pv;
            }
        }
    } else {
        short* dst = which ? Kb : Qb;
#pragma unroll
        for (int i = 0; i < 4; ++i) {
#pragma unroll
            for (int j = 0; j < 4; ++j) {
#pragma unroll
                for (int r = 0; r < 4; ++r) {
                    int lm = wr * 64 + i * 16 + quad * 4 + r;
                    int nn = (m0 & 2047) + lm;
                    int hd = (n0 & 511) + wc * 64 + j * 16 + cc;
                    int h = hd >> 6, dh = hd & 63;
                    float v = acc[i][j][r];
                    if (which == 1 && maskL[lm] == 0) v = 0.0f;   // zero masked K rows
                    dst[((((size_t)b * 8 + h) * 2048 + nn) * 64) + dh] = f2bf(v);
                }
            }
        }
    }
}

// ---------------- flash attention v3 (round-3/6 validated version, verbatim) ----------------
// block = 4 waves, 64 q-rows; s-tiles of 64, 32 iterations, K/V double-buffered.
// QK^T partitioned by s (wave w: s-slice w*16..w*16+15, all 64 t); Q B-frags in regs.
// PV partitioned (t,d) 2x2. P shared via 8KB swizzled LDS. l is per-lane (t=lane&15).
// LDS = 2*8K (K) + 2*8K (V) + 8K (P) = 40KB -> 4 blocks/CU, 16 waves.
__global__ __launch_bounds__(256) void attn_kernel(const short* __restrict__ Q, const short* __restrict__ Kg,
                                                   const short* __restrict__ Vt,
                                                   short* __restrict__ AO) {
    __shared__ __align__(16) char smem[40960];
    short* KbufL = (short*)smem;              // 2 x 4096 shorts
    short* VbufL = (short*)(smem + 16384);    // 2 x 4096 shorts
    short* Pt    = (short*)(smem + 32768);    // [64 t][64 s] swizzled (16B pair-granules)
    float* Lw    = (float*)smem;              // [4 w][64 t]  (reuse buf0 after loop)
    float* Lfin  = (float*)(smem + 1024);     // [64 t] reciprocal sums

    int tid = threadIdx.x;
    int w = tid >> 6, lane = tid & 63;
    int quad = lane >> 4, cc = lane & 15;
    int tg = w >> 1, dh = w & 1;
    int bh = blockIdx.x, b = bh >> 3, h = bh & 7;
    int t0 = blockIdx.y * 64;
    size_t kbase = (size_t)bh * 2048 * 64;
    size_t vbase = (size_t)b * 512 * 2048 + (size_t)h * 64 * 2048;

    // Q B-fragments in registers: qf[tb][kc], B[n=t=tb*16+cc][k=kc*32+quad*8+j]
    short8 qf[4][2];
#pragma unroll
    for (int tb = 0; tb < 4; ++tb)
#pragma unroll
        for (int kc = 0; kc < 2; ++kc)
            qf[tb][kc] = *(const short8*)(Q + kbase + (size_t)(t0 + tb * 16 + cc) * 64 + kc * 32 + quad * 8);

    // loop-invariant LDS offsets (shorts)
    int c7 = cc & 7;
    int koff[2], poff_w[4], aoff[2][2], voff[2][2];
#pragma unroll
    for (int kc = 0; kc < 2; ++kc)
        koff[kc] = (w * 16 + cc) * 64 + (((kc * 4 + quad) ^ c7) * 8);
#pragma unroll
    for (int tb = 0; tb < 4; ++tb)
        poff_w[tb] = (tb * 16 + cc) * 64 + (((w * 2 + (quad >> 1)) ^ c7) * 8) + (quad & 1) * 4;
#pragma unroll
    for (int mb = 0; mb < 2; ++mb)
#pragma unroll
        for (int kc = 0; kc < 2; ++kc)
            aoff[mb][kc] = (tg * 32 + mb * 16 + cc) * 64 + (((kc * 4 + quad) ^ c7) * 8);
#pragma unroll
    for (int db = 0; db < 2; ++db)
#pragma unroll
        for (int kc = 0; kc < 2; ++kc)
            voff[db][kc] = (dh * 32 + db * 16 + cc) * 64 + (((kc * 4 + quad) ^ c7) * 8);

    float4_ o[2][2] = {};            // O[t=tg*32+mb*16+quad*4+r][d=dh*32+db*16+cc]
    float lp[4] = {0.f, 0.f, 0.f, 0.f};  // per-lane partial row sums, t = tb*16+cc

    // prologue: stage tile 0 into buffer 0
#pragma unroll
    for (int pass = 0; pass < 4; ++pass) {
        int slot = pass * 256 + tid;
        if (slot < 512) {
            int s = slot >> 3, c = slot & 7;
            gload_lds16(Kg + kbase + (size_t)s * 64 + ((c ^ (s & 7)) * 8), KbufL + slot * 8);
        } else {
            int q = slot - 512;
            int d = q >> 3, c = q & 7;
            gload_lds16(Vt + vbase + (size_t)d * 2048 + ((c ^ (d & 7)) * 8), VbufL + q * 8);
        }
    }

    for (int it = 0; it < 32; ++it) {
        int cur = it & 1;
        const short* Kt  = KbufL + cur * 4096;
        const short* Vtt = VbufL + cur * 4096;
        __syncthreads();   // DMA(it) drained+visible; prev tile's readers done with buf[cur^1]

        if (it < 31) {     // prefetch tile it+1 into the other buffer
            int s1 = (it + 1) * 64;
            short* Kn = KbufL + (cur ^ 1) * 4096;
            short* Vn = VbufL + (cur ^ 1) * 4096;
#pragma unroll
            for (int pass = 0; pass < 4; ++pass) {
                int slot = pass * 256 + tid;
                if (slot < 512) {
                    int s = slot >> 3, c = slot & 7;
                    gload_lds16(Kg + kbase + (size_t)(s1 + s) * 64 + ((c ^ (s & 7)) * 8), Kn + slot * 8);
                } else {
                    int q = slot - 512;
                    int d = q >> 3, c = q & 7;
                    gload_lds16(Vt + vbase + (size_t)d * 2048 + s1 + ((c ^ (d & 7)) * 8), Vn + q * 8);
                }
            }
        }

        // ---- QK^T: wave w computes S^T[s=w*16+quad*4+r][t=0..63], exp2, write P ----
        short8 kf0 = *(const short8*)(Kt + koff[0]);
        short8 kf1 = *(const short8*)(Kt + koff[1]);
        float4_ acc[4];
#pragma unroll
        for (int tb = 0; tb < 4; ++tb) {
            float4_ a = {0.f, 0.f, 0.f, 0.f};
            a = __builtin_amdgcn_mfma_f32_16x16x32_bf16(kf0, qf[tb][0], a, 0, 0, 0);
            a = __builtin_amdgcn_mfma_f32_16x16x32_bf16(kf1, qf[tb][1], a, 0, 0, 0);
            acc[tb] = a;
        }
#pragma unroll
        for (int tb = 0; tb < 4; ++tb) {
            float x0 = __builtin_amdgcn_exp2f(acc[tb][0]);
            float x1 = __builtin_amdgcn_exp2f(acc[tb][1]);
            float x2 = __builtin_amdgcn_exp2f(acc[tb][2]);
            float x3 = __builtin_amdgcn_exp2f(acc[tb][3]);
            lp[tb] += (x0 + x1) + (x2 + x3);
            uint2 pw; pw.x = pk2bf(x0, x1); pw.y = pk2bf(x2, x3);
            *(uint2*)(Pt + poff_w[tb]) = pw;
        }
        __syncthreads();   // P complete (cross-wave)

        // ---- PV: wave (tg,dh) computes O[32t][32d] += P[32t][64s] * V^T[32d][64s] ----
        short8 af[2][2], vf[2][2];
#pragma unroll
        for (int mb = 0; mb < 2; ++mb)
#pragma unroll
            for (int kc = 0; kc < 2; ++kc)
                af[mb][kc] = *(const short8*)(Pt + aoff[mb][kc]);
#pragma unroll
        for (int db = 0; db < 2; ++db)
#pragma unroll
            for (int kc = 0; kc < 2; ++kc)
                vf[db][kc] = *(const short8*)(Vtt + voff[db][kc]);
#pragma unroll
        for (int mb = 0; mb < 2; ++mb)
#pragma unroll
            for (int db = 0; db < 2; ++db) {
                o[mb][db] = __builtin_amdgcn_mfma_f32_16x16x32_bf16(af[mb][0], vf[db][0], o[mb][db], 0, 0, 0);
                o[mb][db] = __builtin_amdgcn_mfma_f32_16x16x32_bf16(af[mb][1], vf[db][1], o[mb][db], 0, 0, 0);
            }
    }

    // ---- reduce row sums: cross-quad shuffle, cross-wave via LDS ----
#pragma unroll
    for (int tb = 0; tb < 4; ++tb) {
        lp[tb] += __shfl_xor(lp[tb], 16, 64);
        lp[tb] += __shfl_xor(lp[tb], 32, 64);
    }
    __syncthreads();   // everyone past last QK read of buf1 / PV reads (Lw overlays buf0 only)
    if (lane < 16) {
#pragma unroll
        for (int tb = 0; tb < 4; ++tb) Lw[w * 64 + tb * 16 + lane] = lp[tb];
    }
    __syncthreads();
    if (tid < 64) {
        float s = Lw[tid] + Lw[64 + tid] + Lw[128 + tid] + Lw[192 + tid];
        Lfin[tid] = 1.0f / s;
    }
    __syncthreads();

    // ---- normalize + store bf16 ----
#pragma unroll
    for (int mb = 0; mb < 2; ++mb)
#pragma unroll
        for (int r = 0; r < 4; ++r) {
            int tl = tg * 32 + mb * 16 + quad * 4 + r;
            float inv = Lfin[tl];
            size_t rowbase = ((size_t)(b * 2048 + t0 + tl)) * 512 + h * 64;
#pragma unroll
            for (int db = 0; db < 2; ++db)
                AO[rowbase + dh * 32 + db * 16 + cc] = f2bf(o[mb][db][r] * inv);
        }
}

// ---------------- output GEMM: 64x64 tiles, BK=64, XOR-swizzled (1024 blocks), C fp32 ----------------
__global__ __launch_bounds__(256) void gemm_out(const short* __restrict__ A, const short* __restrict__ B,
                                                float* __restrict__ C) {
    __shared__ short At[64 * 64];   // 8 KB each
    __shared__ short Bt[64 * 64];
    constexpr int K = 512;
    int tid = threadIdx.x;
    int wid = tid >> 6, lane = tid & 63;
    int quad = lane >> 4, cc = lane & 15;
    int c7 = cc & 7;
    int wr = wid >> 1, wc = wid & 1;
    int m0 = blockIdx.y * 64, n0 = blockIdx.x * 64;

    float4_ acc[2][2] = {};

    for (int kk = 0; kk < K; kk += 64) {
#pragma unroll
        for (int p = 0; p < 2; ++p) {
            int slot = p * 256 + tid;          // 0..511
            int r = slot >> 3, c = slot & 7;
            int cs = (c ^ (r & 7)) * 8;
            gload_lds16(A + (size_t)(m0 + r) * K + kk + cs, At + slot * 8);
            gload_lds16(B + (size_t)(n0 + r) * K + kk + cs, Bt + slot * 8);
        }
        __syncthreads();
#pragma unroll
        for (int kc = 0; kc < 2; ++kc) {
            short8 af[2], bf[2];
#pragma unroll
            for (int i = 0; i < 2; ++i)
                af[i] = *(const short8*)(At + (wr * 32 + i * 16 + cc) * 64 + (((kc * 4 + quad) ^ c7) * 8));
#pragma unroll
            for (int j = 0; j < 2; ++j)
                bf[j] = *(const short8*)(Bt + (wc * 32 + j * 16 + cc) * 64 + (((kc * 4 + quad) ^ c7) * 8));
#pragma unroll
            for (int i = 0; i < 2; ++i)
#pragma unroll
                for (int j = 0; j < 2; ++j)
                    acc[i][j] = __builtin_amdgcn_mfma_f32_16x16x32_bf16(af[i], bf[j], acc[i][j], 0, 0, 0);
        }
        __syncthreads();
    }

#pragma unroll
    for (int i = 0; i < 2; ++i)
#pragma unroll
        for (int j = 0; j < 2; ++j)
#pragma unroll
            for (int r = 0; r < 4; ++r) {
                int gm = m0 + wr * 32 + i * 16 + quad * 4 + r;
                int gn = n0 + wc * 32 + j * 16 + cc;
                C[(size_t)gm * 512 + gn] = acc[i][j][r];
            }
}

extern "C" void kernel_launch(void* const* d_in, const int* in_sizes, int n_in,
                              void* d_out, int out_size, void* d_ws, size_t ws_size,
                              hipStream_t stream) {
    const float* X  = (const float*)d_in[0];
    const int* mask = (const int*)d_in[1];
    const float* Wq = (const float*)d_in[2];
    const float* Wk = (const float*)d_in[3];
    const float* Wv = (const float*)d_in[4];
    const float* Wo = (const float*)d_in[5];

    char* ws = (char*)d_ws;
    short* Xbf   = (short*)(ws + 0);              // 8192*512*2       = 8,388,608
    short* Wqkvb = (short*)(ws + 8388608);        // 1536*512*2       = 1,572,864
    short* Wob   = (short*)(ws + 9961472);        // 512*512*2        =   524,288
    short* Qb    = (short*)(ws + 10485760);       // [b,h,n,dh] bf16  = 8,388,608
    short* Kb    = (short*)(ws + 18874368);       // [b,h,n,dh] bf16  = 8,388,608
    short* Vtb   = (short*)(ws + 27262976);       // [b,dv,n]  bf16   = 8,388,608
    short* AOb   = (short*)(ws + 35651584);       // [b,n,512] bf16   = 8,388,608

    cvt_kernel<<<5120, 256, 0, stream>>>(X, Wq, Wk, Wv, Wo, Xbf, Wqkvb, Wob);
    gemm_qkv<<<dim3(12, 64), 256, 0, stream>>>(Xbf, Wqkvb, mask, Qb, Kb, Vtb);
    attn_kernel<<<dim3(32, 32), 256, 0, stream>>>(Qb, Kb, Vtb, AOb);
    gemm_out<<<dim3(8, 128), 256, 0, stream>>>(AOb, Wob, (float*)d_out);
}

// Round 9
// 166.384 us; speedup vs baseline: 1.1051x; 1.0482x over previous
//
#include <hip/hip_runtime.h>
#include <hip/hip_bf16.h>

typedef __attribute__((ext_vector_type(8))) short short8;
typedef __attribute__((ext_vector_type(4))) short short4_t;
typedef __attribute__((ext_vector_type(4))) float float4_;

#define LOG2E 1.4426950408889634f

__device__ __forceinline__ short f2bf(float f) {
    unsigned int u = __builtin_bit_cast(unsigned int, f);
    u = (u + 0x7FFFu + ((u >> 16) & 1u)) >> 16;
    return (short)u;
}

// pack two floats to bf16x2 (round-half-up): low short = a, high = b
__device__ __forceinline__ unsigned pk2bf(float a, float b) {
    unsigned ua = __builtin_bit_cast(unsigned, a) + 0x8000u;
    unsigned ub = __builtin_bit_cast(unsigned, b) + 0x8000u;
    return __builtin_amdgcn_perm(ub, ua, 0x07060302);
}

__device__ __forceinline__ void gload_lds16(const short* g, short* l) {
    __builtin_amdgcn_global_load_lds((const __attribute__((address_space(1))) void*)g,
                                     (__attribute__((address_space(3))) void*)l, 16, 0, 0);
}

// ---------------- convert fp32 -> bf16 (fold SCALE*LOG2E into Wq; stack Wq|Wk|Wv) ----------------
__global__ __launch_bounds__(256) void cvt_kernel(
    const float* __restrict__ X, const float* __restrict__ Wq, const float* __restrict__ Wk,
    const float* __restrict__ Wv, const float* __restrict__ Wo,
    short* __restrict__ Xb, short* __restrict__ Wqkvb, short* __restrict__ Wob) {
    int i = blockIdx.x * 256 + threadIdx.x;
    const float* src; short* dst; float sc = 1.0f;
    if (i < 1048576) { src = X + (size_t)i * 4; dst = Xb + (size_t)i * 4; }
    else {
        int w = i - 1048576; int sec = w >> 16; int j = (w & 65535) * 4;
        if (sec == 0)      { src = Wq + j; dst = Wqkvb + j; sc = 0.125f * LOG2E; }
        else if (sec == 1) { src = Wk + j; dst = Wqkvb + 262144 + j; }
        else if (sec == 2) { src = Wv + j; dst = Wqkvb + 524288 + j; }
        else               { src = Wo + j; dst = Wob + j; }
    }
    float4 v = *(const float4*)src;
    short4_t o;
    o[0] = f2bf(v.x * sc); o[1] = f2bf(v.y * sc); o[2] = f2bf(v.z * sc); o[3] = f2bf(v.w * sc);
    *(short4_t*)dst = o;
}

// ---------------- fused QKV projection GEMM, BK=64, XOR-swizzled LDS ----------------
// C[m,n] = sum_k X[m,k]*Wqkv[n,k]; n<512: Q scatter; <1024: K scatter (mask-zeroed); else V^T packed
__global__ __launch_bounds__(256) void gemm_qkv(const short* __restrict__ A, const short* __restrict__ B,
                                                const int* __restrict__ mask,
                                                short* __restrict__ Qb, short* __restrict__ Kb,
                                                short* __restrict__ Vtb) {
    __shared__ short At[128 * 64];    // 16 KB, row=64 shorts, k-chunks XOR-swizzled by row&7
    __shared__ short Bt[128 * 64];
    __shared__ int maskL[128];
    constexpr int K = 512;
    int tid = threadIdx.x;
    int wid = tid >> 6, lane = tid & 63;
    int quad = lane >> 4, cc = lane & 15;
    int c7 = cc & 7;
    int wr = wid >> 1, wc = wid & 1;
    int m0 = blockIdx.y * 128, n0 = blockIdx.x * 128;
    if (tid < 128) maskL[tid] = mask[m0 + tid];

    float4_ acc[4][4] = {};

    for (int kk = 0; kk < K; kk += 64) {
#pragma unroll
        for (int p = 0; p < 4; ++p) {
            int slot = p * 256 + tid;          // 0..1023
            int r = slot >> 3, c = slot & 7;
            int cs = (c ^ (r & 7)) * 8;        // swizzled k-element offset within row
            gload_lds16(A + (size_t)(m0 + r) * K + kk + cs, At + slot * 8);
            gload_lds16(B + (size_t)(n0 + r) * K + kk + cs, Bt + slot * 8);
        }
        __syncthreads();
#pragma unroll
        for (int kc = 0; kc < 2; ++kc) {
            short8 af[4], bf[4];
#pragma unroll
            for (int i = 0; i < 4; ++i)
                af[i] = *(const short8*)(At + (wr * 64 + i * 16 + cc) * 64 + (((kc * 4 + quad) ^ c7) * 8));
#pragma unroll
            for (int j = 0; j < 4; ++j)
                bf[j] = *(const short8*)(Bt + (wc * 64 + j * 16 + cc) * 64 + (((kc * 4 + quad) ^ c7) * 8));
#pragma unroll
            for (int i = 0; i < 4; ++i)
#pragma unroll
                for (int j = 0; j < 4; ++j)
                    acc[i][j] = __builtin_amdgcn_mfma_f32_16x16x32_bf16(af[i], bf[j], acc[i][j], 0, 0, 0);
        }
        __syncthreads();
    }

    int which = n0 >> 9;           // block-uniform: 0=Q, 1=K, 2=V
    int b = m0 >> 11;              // block-uniform batch
    if (which == 2) {
#pragma unroll
        for (int i = 0; i < 4; ++i) {
#pragma unroll
            for (int j = 0; j < 4; ++j) {
                int d = (n0 & 511) + wc * 64 + j * 16 + cc;
                int nn = (m0 & 2047) + wr * 64 + i * 16 + quad * 4;
                short4_t pv;
                pv[0] = f2bf(acc[i][j][0]); pv[1] = f2bf(acc[i][j][1]);
                pv[2] = f2bf(acc[i][j][2]); pv[3] = f2bf(acc[i][j][3]);
                *(short4_t*)(Vtb + ((size_t)(b * 512 + d)) * 2048 + nn) = pv;
            }
        }
    } else {
        short* dst = which ? Kb : Qb;
#pragma unroll
        for (int i = 0; i < 4; ++i) {
#pragma unroll
            for (int j = 0; j < 4; ++j) {
#pragma unroll
                for (int r = 0; r < 4; ++r) {
                    int lm = wr * 64 + i * 16 + quad * 4 + r;
                    int nn = (m0 & 2047) + lm;
                    int hd = (n0 & 511) + wc * 64 + j * 16 + cc;
                    int h = hd >> 6, dh = hd & 63;
                    float v = acc[i][j][r];
                    if (which == 1 && maskL[lm] == 0) v = 0.0f;   // zero masked K rows
                    dst[((((size_t)b * 8 + h) * 2048 + nn) * 64) + dh] = f2bf(v);
                }
            }
        }
    }
}

// ---------------- flash attention v6: r3 structure + global->VGPR->ds_write pipeline ----------------
// Identical math/layout to the validated r3/r6 kernel; only the K/V transport changed:
// plain global loads (prefetch distance 2) + ds_write_b128 replace global_load_lds, so
// barriers no longer drain the prefetch (barrier vmcnt(0) drain only applies to LDS-DMA).
// block = 4 waves, 64 q-rows; s-tiles of 64, 32 iterations, K/V double-buffered.
__global__ __launch_bounds__(256, 4) void attn_kernel(const short* __restrict__ Q, const short* __restrict__ Kg,
                                                      const short* __restrict__ Vt,
                                                      short* __restrict__ AO) {
    __shared__ __align__(16) char smem[40960];
    short* KbufL = (short*)smem;              // 2 x 4096 shorts
    short* VbufL = (short*)(smem + 16384);    // 2 x 4096 shorts
    short* Pt    = (short*)(smem + 32768);    // [64 t][64 s] swizzled (16B pair-granules)
    float* Lw    = (float*)smem;              // [4 w][64 t]  (reuse buf0 after loop)
    float* Lfin  = (float*)(smem + 1024);     // [64 t] reciprocal sums

    int tid = threadIdx.x;
    int w = tid >> 6, lane = tid & 63;
    int quad = lane >> 4, cc = lane & 15;
    int tg = w >> 1, dh = w & 1;
    int bh = blockIdx.x, b = bh >> 3, h = bh & 7;
    int t0 = blockIdx.y * 64;
    size_t kbase = (size_t)bh * 2048 * 64;
    size_t vbase = (size_t)b * 512 * 2048 + (size_t)h * 64 * 2048;

    // Q B-fragments in registers: qf[tb][kc], B[n=t=tb*16+cc][k=kc*32+quad*8+j]
    short8 qf[4][2];
#pragma unroll
    for (int tb = 0; tb < 4; ++tb)
#pragma unroll
        for (int kc = 0; kc < 2; ++kc)
            qf[tb][kc] = *(const short8*)(Q + kbase + (size_t)(t0 + tb * 16 + cc) * 64 + kc * 32 + quad * 8);

    // loop-invariant LDS offsets (shorts)
    int c7 = cc & 7;
    int koff[2], poff_w[4], aoff[2][2], voff[2][2];
#pragma unroll
    for (int kc = 0; kc < 2; ++kc)
        koff[kc] = (w * 16 + cc) * 64 + (((kc * 4 + quad) ^ c7) * 8);
#pragma unroll
    for (int tb = 0; tb < 4; ++tb)
        poff_w[tb] = (tb * 16 + cc) * 64 + (((w * 2 + (quad >> 1)) ^ c7) * 8) + (quad & 1) * 4;
#pragma unroll
    for (int mb = 0; mb < 2; ++mb)
#pragma unroll
        for (int kc = 0; kc < 2; ++kc)
            aoff[mb][kc] = (tg * 32 + mb * 16 + cc) * 64 + (((kc * 4 + quad) ^ c7) * 8);
#pragma unroll
    for (int db = 0; db < 2; ++db)
#pragma unroll
        for (int kc = 0; kc < 2; ++kc)
            voff[db][kc] = (dh * 32 + db * 16 + cc) * 64 + (((kc * 4 + quad) ^ c7) * 8);

    float4_ o[2][2] = {};            // O[t=tg*32+mb*16+quad*4+r][d=dh*32+db*16+cc]
    float lp[4] = {0.f, 0.f, 0.f, 0.f};  // per-lane partial row sums, t = tb*16+cc

    // staging source pointers (same swizzled addresses as the validated DMA version)
    int sA = tid >> 3, cA = tid & 7;
    const short* gK0 = Kg + kbase + (size_t)sA * 64 + ((cA ^ (sA & 7)) * 8);
    const short* gK1 = gK0 + 32 * 64;      // (sA+32)&7 == sA&7
    const short* gV0 = Vt + vbase + (size_t)sA * 2048 + ((cA ^ (sA & 7)) * 8);
    const short* gV1 = gV0 + 32 * 2048;
    int ld0 = tid * 8, ld1 = tid * 8 + 2048;

    // prologue: tile 0 -> regs -> buf0; then start tile 1 loads
    short8 krg0 = *(const short8*)gK0, krg1 = *(const short8*)gK1;
    short8 vrg0 = *(const short8*)gV0, vrg1 = *(const short8*)gV1;
    gK0 += 4096; gK1 += 4096; gV0 += 64; gV1 += 64;
    *(short8*)(KbufL + ld0) = krg0; *(short8*)(KbufL + ld1) = krg1;
    *(short8*)(VbufL + ld0) = vrg0; *(short8*)(VbufL + ld1) = vrg1;
    krg0 = *(const short8*)gK0; krg1 = *(const short8*)gK1;
    vrg0 = *(const short8*)gV0; vrg1 = *(const short8*)gV1;
    gK0 += 4096; gK1 += 4096; gV0 += 64; gV1 += 64;

    for (int it = 0; it < 32; ++it) {
        int cur = it & 1;
        const short* Kt  = KbufL + cur * 4096;
        const short* Vtt = VbufL + cur * 4096;
        __syncthreads();   // buf[cur] (tile it) visible; readers of buf[cur^1] (tile it-1) done

        if (it < 31) {     // commit tile it+1 (in regs, loads issued one full iter ago) to the other buffer
            short* Kn = KbufL + (cur ^ 1) * 4096;
            short* Vn = VbufL + (cur ^ 1) * 4096;
            *(short8*)(Kn + ld0) = krg0; *(short8*)(Kn + ld1) = krg1;
            *(short8*)(Vn + ld0) = vrg0; *(short8*)(Vn + ld1) = vrg1;
        }
        if (it < 30) {     // start loads for tile it+2 (consumed at iter it+1's commit)
            krg0 = *(const short8*)gK0; krg1 = *(const short8*)gK1;
            vrg0 = *(const short8*)gV0; vrg1 = *(const short8*)gV1;
            gK0 += 4096; gK1 += 4096; gV0 += 64; gV1 += 64;
        }

        // ---- QK^T: wave w computes S^T[s=w*16+quad*4+r][t=0..63], exp2, write P ----
        short8 kf0 = *(const short8*)(Kt + koff[0]);
        short8 kf1 = *(const short8*)(Kt + koff[1]);
        float4_ acc[4];
#pragma unroll
        for (int tb = 0; tb < 4; ++tb) {
            float4_ a = {0.f, 0.f, 0.f, 0.f};
            a = __builtin_amdgcn_mfma_f32_16x16x32_bf16(kf0, qf[tb][0], a, 0, 0, 0);
            a = __builtin_amdgcn_mfma_f32_16x16x32_bf16(kf1, qf[tb][1], a, 0, 0, 0);
            acc[tb] = a;
        }
#pragma unroll
        for (int tb = 0; tb < 4; ++tb) {
            float x0 = __builtin_amdgcn_exp2f(acc[tb][0]);
            float x1 = __builtin_amdgcn_exp2f(acc[tb][1]);
            float x2 = __builtin_amdgcn_exp2f(acc[tb][2]);
            float x3 = __builtin_amdgcn_exp2f(acc[tb][3]);
            lp[tb] += (x0 + x1) + (x2 + x3);
            uint2 pw; pw.x = pk2bf(x0, x1); pw.y = pk2bf(x2, x3);
            *(uint2*)(Pt + poff_w[tb]) = pw;
        }
        __syncthreads();   // P complete (cross-wave)

        // ---- PV: wave (tg,dh) computes O[32t][32d] += P[32t][64s] * V^T[32d][64s] ----
        short8 af[2][2], vf[2][2];
#pragma unroll
        for (int mb = 0; mb < 2; ++mb)
#pragma unroll
            for (int kc = 0; kc < 2; ++kc)
                af[mb][kc] = *(const short8*)(Pt + aoff[mb][kc]);
#pragma unroll
        for (int db = 0; db < 2; ++db)
#pragma unroll
            for (int kc = 0; kc < 2; ++kc)
                vf[db][kc] = *(const short8*)(Vtt + voff[db][kc]);
#pragma unroll
        for (int mb = 0; mb < 2; ++mb)
#pragma unroll
            for (int db = 0; db < 2; ++db) {
                o[mb][db] = __builtin_amdgcn_mfma_f32_16x16x32_bf16(af[mb][0], vf[db][0], o[mb][db], 0, 0, 0);
                o[mb][db] = __builtin_amdgcn_mfma_f32_16x16x32_bf16(af[mb][1], vf[db][1], o[mb][db], 0, 0, 0);
            }
    }

    // ---- reduce row sums: cross-quad shuffle, cross-wave via LDS ----
#pragma unroll
    for (int tb = 0; tb < 4; ++tb) {
        lp[tb] += __shfl_xor(lp[tb], 16, 64);
        lp[tb] += __shfl_xor(lp[tb], 32, 64);
    }
    __syncthreads();   // everyone past last QK read of buf1 / PV reads (Lw overlays buf0 only)
    if (lane < 16) {
#pragma unroll
        for (int tb = 0; tb < 4; ++tb) Lw[w * 64 + tb * 16 + lane] = lp[tb];
    }
    __syncthreads();
    if (tid < 64) {
        float s = Lw[tid] + Lw[64 + tid] + Lw[128 + tid] + Lw[192 + tid];
        Lfin[tid] = 1.0f / s;
    }
    __syncthreads();

    // ---- normalize + store bf16 ----
#pragma unroll
    for (int mb = 0; mb < 2; ++mb)
#pragma unroll
        for (int r = 0; r < 4; ++r) {
            int tl = tg * 32 + mb * 16 + quad * 4 + r;
            float inv = Lfin[tl];
            size_t rowbase = ((size_t)(b * 2048 + t0 + tl)) * 512 + h * 64;
#pragma unroll
            for (int db = 0; db < 2; ++db)
                AO[rowbase + dh * 32 + db * 16 + cc] = f2bf(o[mb][db][r] * inv);
        }
}

// ---------------- output GEMM: 64x64 tiles, BK=64, XOR-swizzled (1024 blocks), C fp32 ----------------
__global__ __launch_bounds__(256) void gemm_out(const short* __restrict__ A, const short* __restrict__ B,
                                                float* __restrict__ C) {
    __shared__ short At[64 * 64];   // 8 KB each
    __shared__ short Bt[64 * 64];
    constexpr int K = 512;
    int tid = threadIdx.x;
    int wid = tid >> 6, lane = tid & 63;
    int quad = lane >> 4, cc = lane & 15;
    int c7 = cc & 7;
    int wr = wid >> 1, wc = wid & 1;
    int m0 = blockIdx.y * 64, n0 = blockIdx.x * 64;

    float4_ acc[2][2] = {};

    for (int kk = 0; kk < K; kk += 64) {
#pragma unroll
        for (int p = 0; p < 2; ++p) {
            int slot = p * 256 + tid;          // 0..511
            int r = slot >> 3, c = slot & 7;
            int cs = (c ^ (r & 7)) * 8;
            gload_lds16(A + (size_t)(m0 + r) * K + kk + cs, At + slot * 8);
            gload_lds16(B + (size_t)(n0 + r) * K + kk + cs, Bt + slot * 8);
        }
        __syncthreads();
#pragma unroll
        for (int kc = 0; kc < 2; ++kc) {
            short8 af[2], bf[2];
#pragma unroll
            for (int i = 0; i < 2; ++i)
                af[i] = *(const short8*)(At + (wr * 32 + i * 16 + cc) * 64 + (((kc * 4 + quad) ^ c7) * 8));
#pragma unroll
            for (int j = 0; j < 2; ++j)
                bf[j] = *(const short8*)(Bt + (wc * 32 + j * 16 + cc) * 64 + (((kc * 4 + quad) ^ c7) * 8));
#pragma unroll
            for (int i = 0; i < 2; ++i)
#pragma unroll
                for (int j = 0; j < 2; ++j)
                    acc[i][j] = __builtin_amdgcn_mfma_f32_16x16x32_bf16(af[i], bf[j], acc[i][j], 0, 0, 0);
        }
        __syncthreads();
    }

#pragma unroll
    for (int i = 0; i < 2; ++i)
#pragma unroll
        for (int j = 0; j < 2; ++j)
#pragma unroll
            for (int r = 0; r < 4; ++r) {
                int gm = m0 + wr * 32 + i * 16 + quad * 4 + r;
                int gn = n0 + wc * 32 + j * 16 + cc;
                C[(size_t)gm * 512 + gn] = acc[i][j][r];
            }
}

extern "C" void kernel_launch(void* const* d_in, const int* in_sizes, int n_in,
                              void* d_out, int out_size, void* d_ws, size_t ws_size,
                              hipStream_t stream) {
    const float* X  = (const float*)d_in[0];
    const int* mask = (const int*)d_in[1];
    const float* Wq = (const float*)d_in[2];
    const float* Wk = (const float*)d_in[3];
    const float* Wv = (const float*)d_in[4];
    const float* Wo = (const float*)d_in[5];

    char* ws = (char*)d_ws;
    short* Xbf   = (short*)(ws + 0);              // 8192*512*2       = 8,388,608
    short* Wqkvb = (short*)(ws + 8388608);        // 1536*512*2       = 1,572,864
    short* Wob   = (short*)(ws + 9961472);        // 512*512*2        =   524,288
    short* Qb    = (short*)(ws + 10485760);       // [b,h,n,dh] bf16  = 8,388,608
    short* Kb    = (short*)(ws + 18874368);       // [b,h,n,dh] bf16  = 8,388,608
    short* Vtb   = (short*)(ws + 27262976);       // [b,dv,n]  bf16   = 8,388,608
    short* AOb   = (short*)(ws + 35651584);       // [b,n,512] bf16   = 8,388,608

    cvt_kernel<<<5120, 256, 0, stream>>>(X, Wq, Wk, Wv, Wo, Xbf, Wqkvb, Wob);
    gemm_qkv<<<dim3(12, 64), 256, 0, stream>>>(Xbf, Wqkvb, mask, Qb, Kb, Vtb);
    attn_kernel<<<dim3(32, 32), 256, 0, stream>>>(Qb, Kb, Vtb, AOb);
    gemm_out<<<dim3(8, 128), 256, 0, stream>>>(AOb, Wob, (float*)d_out);
}

// Round 10
// 165.439 us; speedup vs baseline: 1.1114x; 1.0057x over previous
//
#include <hip/hip_runtime.h>
#include <hip/hip_bf16.h>

typedef __attribute__((ext_vector_type(8))) short short8;
typedef __attribute__((ext_vector_type(4))) short short4_t;
typedef __attribute__((ext_vector_type(4))) float float4_;

#define LOG2E 1.4426950408889634f

__device__ __forceinline__ short f2bf(float f) {
    unsigned int u = __builtin_bit_cast(unsigned int, f);
    u = (u + 0x7FFFu + ((u >> 16) & 1u)) >> 16;
    return (short)u;
}

// pack two floats to bf16x2 (round-half-up): low short = a, high = b
__device__ __forceinline__ unsigned pk2bf(float a, float b) {
    unsigned ua = __builtin_bit_cast(unsigned, a) + 0x8000u;
    unsigned ub = __builtin_bit_cast(unsigned, b) + 0x8000u;
    return __builtin_amdgcn_perm(ub, ua, 0x07060302);
}

__device__ __forceinline__ void gload_lds16(const short* g, short* l) {
    __builtin_amdgcn_global_load_lds((const __attribute__((address_space(1))) void*)g,
                                     (__attribute__((address_space(3))) void*)l, 16, 0, 0);
}

// ---------------- convert fp32 -> bf16 (fold SCALE*LOG2E into Wq; stack Wq|Wk|Wv) ----------------
__global__ __launch_bounds__(256) void cvt_kernel(
    const float* __restrict__ X, const float* __restrict__ Wq, const float* __restrict__ Wk,
    const float* __restrict__ Wv, const float* __restrict__ Wo,
    short* __restrict__ Xb, short* __restrict__ Wqkvb, short* __restrict__ Wob) {
    int i = blockIdx.x * 256 + threadIdx.x;
    const float* src; short* dst; float sc = 1.0f;
    if (i < 1048576) { src = X + (size_t)i * 4; dst = Xb + (size_t)i * 4; }
    else {
        int w = i - 1048576; int sec = w >> 16; int j = (w & 65535) * 4;
        if (sec == 0)      { src = Wq + j; dst = Wqkvb + j; sc = 0.125f * LOG2E; }
        else if (sec == 1) { src = Wk + j; dst = Wqkvb + 262144 + j; }
        else if (sec == 2) { src = Wv + j; dst = Wqkvb + 524288 + j; }
        else               { src = Wo + j; dst = Wob + j; }
    }
    float4 v = *(const float4*)src;
    short4_t o;
    o[0] = f2bf(v.x * sc); o[1] = f2bf(v.y * sc); o[2] = f2bf(v.z * sc); o[3] = f2bf(v.w * sc);
    *(short4_t*)dst = o;
}

// ---------------- fused QKV projection GEMM, BK=64, VGPR-pipelined staging ----------------
// C[m,n] = sum_k X[m,k]*Wqkv[n,k]; n<512: Q scatter; <1024: K scatter (mask-zeroed);
// n>=1024: V^T via LDS transpose -> coalesced 256B row-segment stores.
__global__ __launch_bounds__(256) void gemm_qkv(const short* __restrict__ A, const short* __restrict__ B,
                                                const int* __restrict__ mask,
                                                short* __restrict__ Qb, short* __restrict__ Kb,
                                                short* __restrict__ Vtb) {
    __shared__ __align__(16) short smemAB[2 * 8192];   // At | Bt, 16 KB each
    __shared__ int maskL[128];
    short* At = smemAB;
    short* Bt = smemAB + 8192;
    constexpr int K = 512;
    int tid = threadIdx.x;
    int wid = tid >> 6, lane = tid & 63;
    int quad = lane >> 4, cc = lane & 15;
    int c7 = cc & 7;
    int wr = wid >> 1, wc = wid & 1;
    int m0 = blockIdx.y * 128, n0 = blockIdx.x * 128;
    if (tid < 128) maskL[tid] = mask[m0 + tid];

    // staging: 4 chunks (16B) each for A and B per thread, XOR-swizzled k-offsets
    const short* gA[4]; const short* gB[4]; int lofs[4];
#pragma unroll
    for (int p = 0; p < 4; ++p) {
        int slot = p * 256 + tid;          // 0..1023
        int r = slot >> 3, c = slot & 7;
        int cs = (c ^ (r & 7)) * 8;
        gA[p] = A + (size_t)(m0 + r) * K + cs;
        gB[p] = B + (size_t)(n0 + r) * K + cs;
        lofs[p] = slot * 8;
    }
    short8 arg[4], brg[4];
#pragma unroll
    for (int p = 0; p < 4; ++p) { arg[p] = *(const short8*)gA[p]; brg[p] = *(const short8*)gB[p]; }

    float4_ acc[4][4] = {};

    for (int kk = 0; kk < K; kk += 64) {
        __syncthreads();                    // prev iter's LDS reads done
#pragma unroll
        for (int p = 0; p < 4; ++p) {
            *(short8*)(At + lofs[p]) = arg[p];
            *(short8*)(Bt + lofs[p]) = brg[p];
        }
        if (kk < K - 64) {                  // start loads for next tile (waited at next iter's ds_write)
#pragma unroll
            for (int p = 0; p < 4; ++p) {
                arg[p] = *(const short8*)(gA[p] + kk + 64);
                brg[p] = *(const short8*)(gB[p] + kk + 64);
            }
        }
        __syncthreads();                    // tile visible
#pragma unroll
        for (int kc = 0; kc < 2; ++kc) {
            short8 af[4], bf[4];
#pragma unroll
            for (int i = 0; i < 4; ++i)
                af[i] = *(const short8*)(At + (wr * 64 + i * 16 + cc) * 64 + (((kc * 4 + quad) ^ c7) * 8));
#pragma unroll
            for (int j = 0; j < 4; ++j)
                bf[j] = *(const short8*)(Bt + (wc * 64 + j * 16 + cc) * 64 + (((kc * 4 + quad) ^ c7) * 8));
#pragma unroll
            for (int i = 0; i < 4; ++i)
#pragma unroll
                for (int j = 0; j < 4; ++j)
                    acc[i][j] = __builtin_amdgcn_mfma_f32_16x16x32_bf16(af[i], bf[j], acc[i][j], 0, 0, 0);
        }
    }

    int which = n0 >> 9;           // block-uniform: 0=Q, 1=K, 2=V
    int b = m0 >> 11;              // block-uniform batch
    if (which == 2) {
        // ---- V^T via LDS transpose: T[d_l][nn_l], 16B-granule XOR swizzle ----
        __syncthreads();           // K-loop LDS reads done; reuse smemAB as T (32 KB)
        short* T = smemAB;
#pragma unroll
        for (int i = 0; i < 4; ++i) {
#pragma unroll
            for (int j = 0; j < 4; ++j) {
                int d_l = wc * 64 + j * 16 + cc;
                int nnb = wr * 64 + i * 16 + quad * 4;        // 4-aligned
                int G = nnb >> 3, half = (nnb >> 2) & 1;
                int Gs = G ^ (d_l & 15);
                short4_t pv;
                pv[0] = f2bf(acc[i][j][0]); pv[1] = f2bf(acc[i][j][1]);
                pv[2] = f2bf(acc[i][j][2]); pv[3] = f2bf(acc[i][j][3]);
                *(short4_t*)(T + d_l * 128 + Gs * 8 + half * 4) = pv;
            }
        }
        __syncthreads();
        // coalesced store: 2048 granules (16B), lane-consecutive along nn
#pragma unroll
        for (int p = 0; p < 8; ++p) {
            int slot = p * 256 + tid;           // 0..2047
            int d = slot >> 4, G = slot & 15;
            short8 v = *(const short8*)(T + d * 128 + ((G ^ (d & 15)) * 8));
            *(short8*)(Vtb + ((size_t)(b * 512 + (n0 & 511) + d)) * 2048 + (m0 & 2047) + G * 8) = v;
        }
    } else {
        short* dst = which ? Kb : Qb;
#pragma unroll
        for (int i = 0; i < 4; ++i) {
#pragma unroll
            for (int j = 0; j < 4; ++j) {
#pragma unroll
                for (int r = 0; r < 4; ++r) {
                    int lm = wr * 64 + i * 16 + quad * 4 + r;
                    int nn = (m0 & 2047) + lm;
                    int hd = (n0 & 511) + wc * 64 + j * 16 + cc;
                    int h = hd >> 6, dh = hd & 63;
                    float v = acc[i][j][r];
                    if (which == 1 && maskL[lm] == 0) v = 0.0f;   // zero masked K rows
                    dst[((((size_t)b * 8 + h) * 2048 + nn) * 64) + dh] = f2bf(v);
                }
            }
        }
    }
}

// ---------------- flash attention v6 (round-9 validated version, verbatim) ----------------
__global__ __launch_bounds__(256, 4) void attn_kernel(const short* __restrict__ Q, const short* __restrict__ Kg,
                                                      const short* __restrict__ Vt,
                                                      short* __restrict__ AO) {
    __shared__ __align__(16) char smem[40960];
    short* KbufL = (short*)smem;              // 2 x 4096 shorts
    short* VbufL = (short*)(smem + 16384);    // 2 x 4096 shorts
    short* Pt    = (short*)(smem + 32768);    // [64 t][64 s] swizzled (16B pair-granules)
    float* Lw    = (float*)smem;              // [4 w][64 t]  (reuse buf0 after loop)
    float* Lfin  = (float*)(smem + 1024);     // [64 t] reciprocal sums

    int tid = threadIdx.x;
    int w = tid >> 6, lane = tid & 63;
    int quad = lane >> 4, cc = lane & 15;
    int tg = w >> 1, dh = w & 1;
    int bh = blockIdx.x, b = bh >> 3, h = bh & 7;
    int t0 = blockIdx.y * 64;
    size_t kbase = (size_t)bh * 2048 * 64;
    size_t vbase = (size_t)b * 512 * 2048 + (size_t)h * 64 * 2048;

    short8 qf[4][2];
#pragma unroll
    for (int tb = 0; tb < 4; ++tb)
#pragma unroll
        for (int kc = 0; kc < 2; ++kc)
            qf[tb][kc] = *(const short8*)(Q + kbase + (size_t)(t0 + tb * 16 + cc) * 64 + kc * 32 + quad * 8);

    int c7 = cc & 7;
    int koff[2], poff_w[4], aoff[2][2], voff[2][2];
#pragma unroll
    for (int kc = 0; kc < 2; ++kc)
        koff[kc] = (w * 16 + cc) * 64 + (((kc * 4 + quad) ^ c7) * 8);
#pragma unroll
    for (int tb = 0; tb < 4; ++tb)
        poff_w[tb] = (tb * 16 + cc) * 64 + (((w * 2 + (quad >> 1)) ^ c7) * 8) + (quad & 1) * 4;
#pragma unroll
    for (int mb = 0; mb < 2; ++mb)
#pragma unroll
        for (int kc = 0; kc < 2; ++kc)
            aoff[mb][kc] = (tg * 32 + mb * 16 + cc) * 64 + (((kc * 4 + quad) ^ c7) * 8);
#pragma unroll
    for (int db = 0; db < 2; ++db)
#pragma unroll
        for (int kc = 0; kc < 2; ++kc)
            voff[db][kc] = (dh * 32 + db * 16 + cc) * 64 + (((kc * 4 + quad) ^ c7) * 8);

    float4_ o[2][2] = {};
    float lp[4] = {0.f, 0.f, 0.f, 0.f};

    int sA = tid >> 3, cA = tid & 7;
    const short* gK0 = Kg + kbase + (size_t)sA * 64 + ((cA ^ (sA & 7)) * 8);
    const short* gK1 = gK0 + 32 * 64;
    const short* gV0 = Vt + vbase + (size_t)sA * 2048 + ((cA ^ (sA & 7)) * 8);
    const short* gV1 = gV0 + 32 * 2048;
    int ld0 = tid * 8, ld1 = tid * 8 + 2048;

    short8 krg0 = *(const short8*)gK0, krg1 = *(const short8*)gK1;
    short8 vrg0 = *(const short8*)gV0, vrg1 = *(const short8*)gV1;
    gK0 += 4096; gK1 += 4096; gV0 += 64; gV1 += 64;
    *(short8*)(KbufL + ld0) = krg0; *(short8*)(KbufL + ld1) = krg1;
    *(short8*)(VbufL + ld0) = vrg0; *(short8*)(VbufL + ld1) = vrg1;
    krg0 = *(const short8*)gK0; krg1 = *(const short8*)gK1;
    vrg0 = *(const short8*)gV0; vrg1 = *(const short8*)gV1;
    gK0 += 4096; gK1 += 4096; gV0 += 64; gV1 += 64;

    for (int it = 0; it < 32; ++it) {
        int cur = it & 1;
        const short* Kt  = KbufL + cur * 4096;
        const short* Vtt = VbufL + cur * 4096;
        __syncthreads();

        if (it < 31) {
            short* Kn = KbufL + (cur ^ 1) * 4096;
            short* Vn = VbufL + (cur ^ 1) * 4096;
            *(short8*)(Kn + ld0) = krg0; *(short8*)(Kn + ld1) = krg1;
            *(short8*)(Vn + ld0) = vrg0; *(short8*)(Vn + ld1) = vrg1;
        }
        if (it < 30) {
            krg0 = *(const short8*)gK0; krg1 = *(const short8*)gK1;
            vrg0 = *(const short8*)gV0; vrg1 = *(const short8*)gV1;
            gK0 += 4096; gK1 += 4096; gV0 += 64; gV1 += 64;
        }

        short8 kf0 = *(const short8*)(Kt + koff[0]);
        short8 kf1 = *(const short8*)(Kt + koff[1]);
        float4_ acc[4];
#pragma unroll
        for (int tb = 0; tb < 4; ++tb) {
            float4_ a = {0.f, 0.f, 0.f, 0.f};
            a = __builtin_amdgcn_mfma_f32_16x16x32_bf16(kf0, qf[tb][0], a, 0, 0, 0);
            a = __builtin_amdgcn_mfma_f32_16x16x32_bf16(kf1, qf[tb][1], a, 0, 0, 0);
            acc[tb] = a;
        }
#pragma unroll
        for (int tb = 0; tb < 4; ++tb) {
            float x0 = __builtin_amdgcn_exp2f(acc[tb][0]);
            float x1 = __builtin_amdgcn_exp2f(acc[tb][1]);
            float x2 = __builtin_amdgcn_exp2f(acc[tb][2]);
            float x3 = __builtin_amdgcn_exp2f(acc[tb][3]);
            lp[tb] += (x0 + x1) + (x2 + x3);
            uint2 pw; pw.x = pk2bf(x0, x1); pw.y = pk2bf(x2, x3);
            *(uint2*)(Pt + poff_w[tb]) = pw;
        }
        __syncthreads();

        short8 af[2][2], vf[2][2];
#pragma unroll
        for (int mb = 0; mb < 2; ++mb)
#pragma unroll
            for (int kc = 0; kc < 2; ++kc)
                af[mb][kc] = *(const short8*)(Pt + aoff[mb][kc]);
#pragma unroll
        for (int db = 0; db < 2; ++db)
#pragma unroll
            for (int kc = 0; kc < 2; ++kc)
                vf[db][kc] = *(const short8*)(Vtt + voff[db][kc]);
#pragma unroll
        for (int mb = 0; mb < 2; ++mb)
#pragma unroll
            for (int db = 0; db < 2; ++db) {
                o[mb][db] = __builtin_amdgcn_mfma_f32_16x16x32_bf16(af[mb][0], vf[db][0], o[mb][db], 0, 0, 0);
                o[mb][db] = __builtin_amdgcn_mfma_f32_16x16x32_bf16(af[mb][1], vf[db][1], o[mb][db], 0, 0, 0);
            }
    }

#pragma unroll
    for (int tb = 0; tb < 4; ++tb) {
        lp[tb] += __shfl_xor(lp[tb], 16, 64);
        lp[tb] += __shfl_xor(lp[tb], 32, 64);
    }
    __syncthreads();
    if (lane < 16) {
#pragma unroll
        for (int tb = 0; tb < 4; ++tb) Lw[w * 64 + tb * 16 + lane] = lp[tb];
    }
    __syncthreads();
    if (tid < 64) {
        float s = Lw[tid] + Lw[64 + tid] + Lw[128 + tid] + Lw[192 + tid];
        Lfin[tid] = 1.0f / s;
    }
    __syncthreads();

#pragma unroll
    for (int mb = 0; mb < 2; ++mb)
#pragma unroll
        for (int r = 0; r < 4; ++r) {
            int tl = tg * 32 + mb * 16 + quad * 4 + r;
            float inv = Lfin[tl];
            size_t rowbase = ((size_t)(b * 2048 + t0 + tl)) * 512 + h * 64;
#pragma unroll
            for (int db = 0; db < 2; ++db)
                AO[rowbase + dh * 32 + db * 16 + cc] = f2bf(o[mb][db][r] * inv);
        }
}

// ---------------- output GEMM: 64x64 tiles, BK=64, XOR-swizzled (1024 blocks), C fp32 ----------------
__global__ __launch_bounds__(256) void gemm_out(const short* __restrict__ A, const short* __restrict__ B,
                                                float* __restrict__ C) {
    __shared__ short At[64 * 64];   // 8 KB each
    __shared__ short Bt[64 * 64];
    constexpr int K = 512;
    int tid = threadIdx.x;
    int wid = tid >> 6, lane = tid & 63;
    int quad = lane >> 4, cc = lane & 15;
    int c7 = cc & 7;
    int wr = wid >> 1, wc = wid & 1;
    int m0 = blockIdx.y * 64, n0 = blockIdx.x * 64;

    float4_ acc[2][2] = {};

    for (int kk = 0; kk < K; kk += 64) {
#pragma unroll
        for (int p = 0; p < 2; ++p) {
            int slot = p * 256 + tid;          // 0..511
            int r = slot >> 3, c = slot & 7;
            int cs = (c ^ (r & 7)) * 8;
            gload_lds16(A + (size_t)(m0 + r) * K + kk + cs, At + slot * 8);
            gload_lds16(B + (size_t)(n0 + r) * K + kk + cs, Bt + slot * 8);
        }
        __syncthreads();
#pragma unroll
        for (int kc = 0; kc < 2; ++kc) {
            short8 af[2], bf[2];
#pragma unroll
            for (int i = 0; i < 2; ++i)
                af[i] = *(const short8*)(At + (wr * 32 + i * 16 + cc) * 64 + (((kc * 4 + quad) ^ c7) * 8));
#pragma unroll
            for (int j = 0; j < 2; ++j)
                bf[j] = *(const short8*)(Bt + (wc * 32 + j * 16 + cc) * 64 + (((kc * 4 + quad) ^ c7) * 8));
#pragma unroll
            for (int i = 0; i < 2; ++i)
#pragma unroll
                for (int j = 0; j < 2; ++j)
                    acc[i][j] = __builtin_amdgcn_mfma_f32_16x16x32_bf16(af[i], bf[j], acc[i][j], 0, 0, 0);
        }
        __syncthreads();
    }

#pragma unroll
    for (int i = 0; i < 2; ++i)
#pragma unroll
        for (int j = 0; j < 2; ++j)
#pragma unroll
            for (int r = 0; r < 4; ++r) {
                int gm = m0 + wr * 32 + i * 16 + quad * 4 + r;
                int gn = n0 + wc * 32 + j * 16 + cc;
                C[(size_t)gm * 512 + gn] = acc[i][j][r];
            }
}

extern "C" void kernel_launch(void* const* d_in, const int* in_sizes, int n_in,
                              void* d_out, int out_size, void* d_ws, size_t ws_size,
                              hipStream_t stream) {
    const float* X  = (const float*)d_in[0];
    const int* mask = (const int*)d_in[1];
    const float* Wq = (const float*)d_in[2];
    const float* Wk = (const float*)d_in[3];
    const float* Wv = (const float*)d_in[4];
    const float* Wo = (const float*)d_in[5];

    char* ws = (char*)d_ws;
    short* Xbf   = (short*)(ws + 0);              // 8192*512*2       = 8,388,608
    short* Wqkvb = (short*)(ws + 8388608);        // 1536*512*2       = 1,572,864
    short* Wob   = (short*)(ws + 9961472);        // 512*512*2        =   524,288
    short* Qb    = (short*)(ws + 10485760);       // [b,h,n,dh] bf16  = 8,388,608
    short* Kb    = (short*)(ws + 18874368);       // [b,h,n,dh] bf16  = 8,388,608
    short* Vtb   = (short*)(ws + 27262976);       // [b,dv,n]  bf16   = 8,388,608
    short* AOb   = (short*)(ws + 35651584);       // [b,n,512] bf16   = 8,388,608

    cvt_kernel<<<5120, 256, 0, stream>>>(X, Wq, Wk, Wv, Wo, Xbf, Wqkvb, Wob);
    gemm_qkv<<<dim3(12, 64), 256, 0, stream>>>(Xbf, Wqkvb, mask, Qb, Kb, Vtb);
    attn_kernel<<<dim3(32, 32), 256, 0, stream>>>(Qb, Kb, Vtb, AOb);
    gemm_out<<<dim3(8, 128), 256, 0, stream>>>(AOb, Wob, (float*)d_out);
}